// Round 5
// baseline (157.300 us; speedup 1.0000x reference)
//
#include <hip/hip_runtime.h>
#include <hip/hip_bf16.h>

#define B_ 4
#define C_ 128
#define N_ 8192
#define K_ 16
#define NBLK_STATS 2048

typedef __attribute__((ext_vector_type(8))) short short8;
typedef __attribute__((ext_vector_type(4))) float floatx4;

static __device__ __forceinline__ unsigned short f2b(float x) {
  return __builtin_bit_cast(unsigned short, __float2bfloat16(x));
}
// unpack 8 bf16 (uint4) -> 8 floats.
static __device__ __forceinline__ void unpack8(uint4 u, float* f) {
  const unsigned* w = (const unsigned*)&u;
#pragma unroll
  for (int i = 0; i < 4; i++) {
    f[2 * i]     = __builtin_bit_cast(float, w[i] << 16);
    f[2 * i + 1] = __builtin_bit_cast(float, w[i] & 0xffff0000u);
  }
}

// workspace byte offsets
#define OFF_LOCAL 0ULL
#define OFF_EDGE  8388608ULL
#define OFF_WBF1  16777216ULL
#define OFF_WBF2  16809984ULL
#define OFF_PART  16842752ULL
#define OFF_COEF  21037056ULL
#define WS_BYTES  21039104ULL

// K0: cast W1,W2 -> bf16, same [o][c] layout.
__global__ __launch_bounds__(256) void k_prep(const float* __restrict__ w1,
    const float* __restrict__ w2, unsigned short* __restrict__ wbf1,
    unsigned short* __restrict__ wbf2) {
  int i = blockIdx.x * 256 + threadIdx.x;
  wbf1[i] = f2b(w1[i]);
  wbf2[i] = f2b(w2[i]);
}

// XCD-affine swizzle: batch b pinned to XCDs {2b, 2b+1} (blockIdx%8 round-robin).
static __device__ __forceinline__ void swz(int bid, int& b, int& chunk) {
  b = (bid & 7) >> 1;
  chunk = ((bid >> 3) << 1) | (bid & 1);
}

// K1: MFMA dual-GEMM, (b,n,o) bf16 output. 1024 blocks x 32 n.
// Waves 0-1: W1 -> local; waves 2-3: W2 -> edge (g split across waves).
__global__ __launch_bounds__(256, 4) void k_gemm(const float* __restrict__ feat,
    const unsigned short* __restrict__ wbf1, const unsigned short* __restrict__ wbf2,
    unsigned short* __restrict__ localB, unsigned short* __restrict__ edgeB) {
  __shared__ __align__(16) unsigned short lds_u[8704];  // stage: [c][36]; out: 2 x [32][136]
  const int t = threadIdx.x;
  int b, chunk; swz(blockIdx.x, b, chunk);
  const int n0 = chunk << 5;
  const float* fb = feat + (size_t)b * C_ * N_;
  // stage feat 128c x 32n fp32 -> bf16 LDS [c][36]
#pragma unroll
  for (int i = 0; i < 4; i++) {
    int c = i * 32 + (t >> 3);
    int n4 = (t & 7) << 2;
    floatx4 f = __builtin_nontemporal_load((const floatx4*)&fb[(size_t)c * N_ + n0 + n4]);
    ushort4 u = make_ushort4(f2b(f[0]), f2b(f[1]), f2b(f[2]), f2b(f[3]));
    *(ushort4*)&lds_u[c * 36 + n4] = u;
  }
  __syncthreads();
  const int lane = t & 63, wv = t >> 6, l15 = lane & 15, q = lane >> 4;
  const int gw = wv >> 1;         // 0: local/W1, 1: edge/W2
  const int nt = wv & 1;          // n-subtile (16 n)
  short8 bfrag[4];
#pragma unroll
  for (int ks = 0; ks < 4; ks++)
#pragma unroll
    for (int j = 0; j < 8; j++)
      bfrag[ks][j] = (short)lds_u[(ks * 32 + q * 8 + j) * 36 + nt * 16 + l15];
  __syncthreads();  // all staging reads done; reuse LDS as output tiles

  const unsigned short* Wg = gw ? wbf2 : wbf1;
  floatx4 acc[8];
#pragma unroll
  for (int mt = 0; mt < 8; mt++) acc[mt] = (floatx4){0.f, 0.f, 0.f, 0.f};
#pragma unroll
  for (int ks = 0; ks < 4; ks++) {
    short8 af[8];
#pragma unroll
    for (int mt = 0; mt < 8; mt++)
      af[mt] = *(const short8*)(Wg + (size_t)(mt * 16 + l15) * 128 + ks * 32 + q * 8);
#pragma unroll
    for (int mt = 0; mt < 8; mt++)
      acc[mt] = __builtin_amdgcn_mfma_f32_16x16x32_bf16(af[mt], bfrag[ks], acc[mt], 0, 0, 0);
  }
  // D[o = mt*16+q*4+r][n = nt*16+l15] -> outtile_g[n][o]
  unsigned short* ot = lds_u + gw * 4352;
#pragma unroll
  for (int mt = 0; mt < 8; mt++) {
    ushort4 u = make_ushort4(f2b(acc[mt][0]), f2b(acc[mt][1]), f2b(acc[mt][2]), f2b(acc[mt][3]));
    *(ushort4*)&ot[(nt * 16 + l15) * 136 + mt * 16 + q * 4] = u;
  }
  __syncthreads();
#pragma unroll
  for (int g = 0; g < 2; g++) {
    unsigned short* dst = (g ? edgeB : localB) + ((size_t)b * N_ + n0) * 128;
#pragma unroll
    for (int i = 0; i < 2; i++) {
      int ng = i * 16 + (t >> 4);
      int o8 = (t & 15) * 8;
      float4 v = *(float4*)&lds_u[g * 4352 + ng * 136 + o8];
      *(float4*)&dst[(size_t)ng * 128 + o8] = v;
    }
  }
}

// K2: stats. 2048 blocks x 16 n. All 16 neighbors in flight per thread.
__global__ __launch_bounds__(256, 4) void k_stats(const unsigned short* __restrict__ localB,
    const unsigned short* __restrict__ edgeB, const int* __restrict__ knn,
    float* __restrict__ partials) {
  __shared__ int knn_s[256];
  __shared__ float red[512];
  const int t = threadIdx.x;
  int b, chunk; swz(blockIdx.x, b, chunk);
  const int n0 = chunk << 4;
  red[t] = 0.f; red[t + 256] = 0.f;
  knn_s[t] = knn[((size_t)b * N_ + n0) * K_ + t];
  __syncthreads();
  const int slot = t >> 4;
  const int co = t & 15;
  const unsigned short* lb = localB + (size_t)b * N_ * 128;
  const unsigned short* eb = edgeB + (size_t)b * N_ * 128;
  uint4 lu = *(const uint4*)&lb[(size_t)(n0 + slot) * 128 + co * 8];
  float l[8]; unpack8(lu, l);
  uint4 eu[16];
#pragma unroll
  for (int k = 0; k < 16; k++)
    eu[k] = *(const uint4*)&eb[(size_t)knn_s[slot * 16 + k] * 128 + co * 8];
  float se[8] = {0,0,0,0,0,0,0,0}, se2[8] = {0,0,0,0,0,0,0,0};
#pragma unroll
  for (int k = 0; k < 16; k++) {
    float e[8]; unpack8(eu[k], e);
#pragma unroll
    for (int j = 0; j < 8; j++) { se[j] += e[j]; se2[j] = fmaf(e[j], e[j], se2[j]); }
  }
  float lS[8], lQ[8], dS[8], dQ[8];
#pragma unroll
  for (int j = 0; j < 8; j++) {
    lS[j] = l[j];
    lQ[j] = l[j] * l[j];
    dS[j] = se[j] - 16.f * l[j];
    dQ[j] = fmaf(-2.f * l[j], se[j], se2[j]) + 16.f * lQ[j];
  }
#pragma unroll
  for (int off = 16; off <= 32; off <<= 1) {
#pragma unroll
    for (int j = 0; j < 8; j++) {
      lS[j] += __shfl_xor(lS[j], off);
      lQ[j] += __shfl_xor(lQ[j], off);
      dS[j] += __shfl_xor(dS[j], off);
      dQ[j] += __shfl_xor(dQ[j], off);
    }
  }
  if ((t & 48) == 0) {
    int ch = co * 8;
#pragma unroll
    for (int j = 0; j < 8; j++) {
      atomicAdd(&red[ch + j], lS[j]);
      atomicAdd(&red[128 + ch + j], dS[j]);
      atomicAdd(&red[256 + ch + j], lQ[j]);
      atomicAdd(&red[384 + ch + j], dQ[j]);
    }
  }
  __syncthreads();
  float* pb = partials + (size_t)blockIdx.x * 512;
  pb[t] = red[t];
  pb[t + 256] = red[t + 256];
}

// K3: reduce partials -> per-channel affine coefs y = a*x + b.
__global__ __launch_bounds__(256) void k_coef(const float* __restrict__ partials,
    const float* __restrict__ gamma, const float* __restrict__ beta,
    float* __restrict__ coef) {
  const int c = blockIdx.x;
  const int t = threadIdx.x;
  float s = 0.f, q = 0.f;
  for (int j = t; j < NBLK_STATS; j += 256) {
    s += partials[(size_t)j * 512 + c];
    q += partials[(size_t)j * 512 + 256 + c];
  }
#pragma unroll
  for (int off = 32; off > 0; off >>= 1) {
    s += __shfl_down(s, off);
    q += __shfl_down(q, off);
  }
  __shared__ float rs[4], rq[4];
  int w = t >> 6;
  if ((t & 63) == 0) { rs[w] = s; rq[w] = q; }
  __syncthreads();
  if (t == 0) {
    float S = rs[0] + rs[1] + rs[2] + rs[3];
    float Q = rq[0] + rq[1] + rq[2] + rq[3];
    float cnt = (c < 128) ? (float)(B_ * N_) : (float)(B_ * N_ * K_);
    float mean = S / cnt;
    float var = fmaxf(Q / cnt - mean * mean, 0.f);
    float a = gamma[c] * rsqrtf(var + 1e-5f);
    coef[c] = a;
    coef[256 + c] = beta[c] - mean * a;
  }
}

// K4: output. 1024 blocks x 32 n; per half: 16-deep gather batch. NT final stores.
__global__ __launch_bounds__(256, 3) void k_out(const unsigned short* __restrict__ localB,
    const unsigned short* __restrict__ edgeB, const int* __restrict__ knn,
    const float* __restrict__ coef, float* __restrict__ out) {
  __shared__ float tile[256][36];
  __shared__ int knn_s[512];
  const int t = threadIdx.x;
  int b, chunk; swz(blockIdx.x, b, chunk);
  const int n0 = chunk << 5;
  const int* kb = knn + ((size_t)b * N_ + n0) * K_;
  knn_s[t] = kb[t];
  knn_s[t + 256] = kb[t + 256];
  __syncthreads();
  const int slot = t >> 4;
  const int co = t & 15;
  float caL[8], cbL[8], caE[8], cbE[8];
  *(float4*)&caL[0] = *(const float4*)&coef[co * 8];
  *(float4*)&caL[4] = *(const float4*)&coef[co * 8 + 4];
  *(float4*)&caE[0] = *(const float4*)&coef[128 + co * 8];
  *(float4*)&caE[4] = *(const float4*)&coef[128 + co * 8 + 4];
  *(float4*)&cbL[0] = *(const float4*)&coef[256 + co * 8];
  *(float4*)&cbL[4] = *(const float4*)&coef[256 + co * 8 + 4];
  *(float4*)&cbE[0] = *(const float4*)&coef[384 + co * 8];
  *(float4*)&cbE[4] = *(const float4*)&coef[384 + co * 8 + 4];
  const unsigned short* lb = localB + (size_t)b * N_ * 128;
  const unsigned short* eb = edgeB + (size_t)b * N_ * 128;
#pragma unroll
  for (int h = 0; h < 2; h++) {
    int nl = slot + h * 16;
    uint4 lu = *(const uint4*)&lb[(size_t)(n0 + nl) * 128 + co * 8];
    float l[8]; unpack8(lu, l);
    float hc[8];
#pragma unroll
    for (int j = 0; j < 8; j++) hc[j] = fmaf(-l[j], caE[j], cbE[j]);
    uint4 eu[16];
#pragma unroll
    for (int k = 0; k < 16; k++)
      eu[k] = *(const uint4*)&eb[(size_t)knn_s[nl * 16 + k] * 128 + co * 8];
    float acc[8] = {0,0,0,0,0,0,0,0};
#pragma unroll
    for (int k = 0; k < 16; k++) {
      float e[8]; unpack8(eu[k], e);
#pragma unroll
      for (int j = 0; j < 8; j++)
        acc[j] += fmaxf(fmaf(e[j], caE[j], hc[j]), 0.f);
    }
#pragma unroll
    for (int j = 0; j < 8; j++) {
      tile[co * 8 + j][nl] = fmaxf(fmaf(l[j], caL[j], cbL[j]), 0.f);
      tile[128 + co * 8 + j][nl] = acc[j] * 0.0625f;
    }
  }
  __syncthreads();
  float* ob = out + (size_t)b * 256 * N_;
  const int cr = t >> 3;
  const int n4 = (t & 7) << 2;
#pragma unroll
  for (int p = 0; p < 8; p++) {
    int c = (p << 5) + cr;
    floatx4 v = *(floatx4*)&tile[c][n4];
    __builtin_nontemporal_store(v, (floatx4*)&ob[(size_t)c * N_ + n0 + n4]);
  }
}

extern "C" void kernel_launch(void* const* d_in, const int* in_sizes, int n_in,
                              void* d_out, int out_size, void* d_ws, size_t ws_size,
                              hipStream_t stream) {
  const float* feat  = (const float*)d_in[0];
  const int*   knn   = (const int*)d_in[1];
  const float* w1    = (const float*)d_in[2];
  const float* w2    = (const float*)d_in[3];
  const float* gamma = (const float*)d_in[4];
  const float* beta  = (const float*)d_in[5];
  if (ws_size < WS_BYTES) return;
  unsigned char* ws = (unsigned char*)d_ws;
  unsigned short* localB = (unsigned short*)(ws + OFF_LOCAL);
  unsigned short* edgeB  = (unsigned short*)(ws + OFF_EDGE);
  unsigned short* wbf1   = (unsigned short*)(ws + OFF_WBF1);
  unsigned short* wbf2   = (unsigned short*)(ws + OFF_WBF2);
  float* partials        = (float*)(ws + OFF_PART);
  float* coef            = (float*)(ws + OFF_COEF);
  float* outp = (float*)d_out;

  hipLaunchKernelGGL(k_prep, dim3(64), dim3(256), 0, stream, w1, w2, wbf1, wbf2);
  hipLaunchKernelGGL(k_gemm, dim3(1024), dim3(256), 0, stream, feat, wbf1, wbf2, localB, edgeB);
  hipLaunchKernelGGL(k_stats, dim3(2048), dim3(256), 0, stream, localB, edgeB, knn, partials);
  hipLaunchKernelGGL(k_coef, dim3(256), dim3(256), 0, stream, partials, gamma, beta, coef);
  hipLaunchKernelGGL(k_out, dim3(1024), dim3(256), 0, stream, localB, edgeB, knn, coef, outp);
}